// Round 2
// baseline (132.688 us; speedup 1.0000x reference)
//
#include <hip/hip_runtime.h>

#define SEQ   1024
#define BATCH 32
#define DIM   256   // 64 float4 per row

// ---------------------------------------------------------------------------
// Kernel 1: per-batch inclusive scan of durations (1024 tokens; 256 threads x
// 4 tokens, LDS Hillis-Steele), then scatter frame -> within-token position:
// pos[f*BATCH + b] = f - start(token).  Also writes totals[b] so the gather
// can mask tail frames -- pos needs NO initialization (rows f >= total[b]
// are never read).
// ---------------------------------------------------------------------------
__global__ __launch_bounds__(256) void pe_scan_scatter(const int* __restrict__ dur,
                                                       int* __restrict__ pos,
                                                       int* __restrict__ totals,
                                                       int T) {
    const int b = blockIdx.x;    // batch element, 0..31
    const int t = threadIdx.x;   // 0..255
    __shared__ int ssum[256];

    // 4 consecutive tokens for this thread (column b, stride BATCH)
    int d[4];
    const int base = (t * 4) * BATCH + b;
#pragma unroll
    for (int i = 0; i < 4; ++i) d[i] = dur[base + i * BATCH];

    ssum[t] = d[0] + d[1] + d[2] + d[3];
    __syncthreads();

    // Hillis-Steele inclusive scan over 256 per-thread sums
    for (int off = 1; off < 256; off <<= 1) {
        int v = (t >= off) ? ssum[t - off] : 0;
        __syncthreads();
        ssum[t] += v;
        __syncthreads();
    }

    if (t == 255) totals[b] = ssum[255];

    int start = (t > 0) ? ssum[t - 1] : 0;   // exclusive prefix for token 4t
#pragma unroll
    for (int i = 0; i < 4; ++i) {
        for (int k = 0; k < d[i]; ++k) {     // d[i] in [0, 8)
            int f = start + k;
            if (f < T) pos[f * BATCH + b] = k;
        }
        start += d[i];
    }
}

// ---------------------------------------------------------------------------
// Kernel 2: gather. One float4 (16B) per thread, fully coalesced writes.
// row is wave-uniform (64 lanes per row) -> pos/totals loads broadcast.
// Only encoding rows 0..7 are ever touched (dur < 8) -> L1-resident.
// Tail frames (f >= totals[b]) write zeros without touching pos.
// ---------------------------------------------------------------------------
__global__ __launch_bounds__(256) void pe_gather(const int* __restrict__ pos,
                                                 const int* __restrict__ totals,
                                                 const float4* __restrict__ enc,
                                                 float4* __restrict__ out,
                                                 int n4) {
    int idx = blockIdx.x * blockDim.x + threadIdx.x;
    if (idx >= n4) return;
    int row = idx >> 6;          // (frame, batch) row
    int f   = row >> 5;          // frame index  (BATCH == 32)
    int b   = row & 31;          // batch index
    float4 v = {0.f, 0.f, 0.f, 0.f};
    if (f < totals[b]) {
        int p = pos[row];        // within-token position, 0..7
        v = enc[p * (DIM / 4) + (idx & 63)];
    }
    out[idx] = v;
}

extern "C" void kernel_launch(void* const* d_in, const int* in_sizes, int n_in,
                              void* d_out, int out_size, void* d_ws, size_t ws_size,
                              hipStream_t stream) {
    const int*   dur = (const int*)d_in[0];     // (SEQ, BATCH) int32
    const float* enc = (const float*)d_in[1];   // (1000, DIM) float32
    float*       out = (float*)d_out;           // (T, BATCH, DIM) float32

    const int T     = out_size / (BATCH * DIM);
    const int nrows = T * BATCH;
    int* pos    = (int*)d_ws;
    int* totals = pos + nrows;                  // 32 ints after pos

    pe_scan_scatter<<<BATCH, 256, 0, stream>>>(dur, pos, totals, T);

    const int n4 = nrows * (DIM / 4);
    pe_gather<<<(n4 + 255) / 256, 256, 0, stream>>>(
        pos, totals, (const float4*)enc, (float4*)out, n4);
}